// Round 10
// baseline (893.023 us; speedup 1.0000x reference)
//
#include <hip/hip_runtime.h>
#include <math.h>

#define S_LEN 2048
#define NH 16
#define HD 64
#define DMODEL 1024
#define BATCH 4
#define M_TOT (BATCH * S_LEN)   // 8192

typedef __attribute__((ext_vector_type(8))) short bf16x8;
typedef __attribute__((ext_vector_type(4))) float f32x4;

#define CK 0.18033688f   // (1/sqrt(64)) * log2(e), folded into Q at projection

__device__ __forceinline__ unsigned short f2bf_rne(float f) {
    unsigned u = __float_as_uint(f);
    u += 0x7fffu + ((u >> 16) & 1u);
    return (unsigned short)(u >> 16);
}

__device__ __forceinline__ void gld16(unsigned short* lds, const unsigned short* g) {
    __builtin_amdgcn_global_load_lds(
        (const __attribute__((address_space(1))) void*)g,
        (__attribute__((address_space(3))) void*)lds, 16, 0, 0);
}

// ---------------------------------------------------------------------------
// cvt_x: fp32 -> bf16, x [8192,1024]
// ---------------------------------------------------------------------------
__global__ __launch_bounds__(256) void cvt_x(
    const float* __restrict__ x, unsigned short* __restrict__ xb)
{
    size_t i = ((size_t)blockIdx.x * 256 + threadIdx.x) * 4;
    float4 v = *(const float4*)(x + i);
    unsigned short t[4];
    t[0] = f2bf_rne(v.x); t[1] = f2bf_rne(v.y);
    t[2] = f2bf_rne(v.z); t[3] = f2bf_rne(v.w);
    *(uint2*)(xb + i) = *(uint2*)t;
}

// ---------------------------------------------------------------------------
// cvt_wT: transpose + convert W [k][n] fp32 -> WT [n][k=1024] bf16.
// z=0..2: Wq/Wk/Wv (1024x1024).  z=3: Wf (1024x64) -> WfT [64][1024].
// ---------------------------------------------------------------------------
__global__ __launch_bounds__(256) void cvt_wT(
    const float* __restrict__ Wq, const float* __restrict__ Wk,
    const float* __restrict__ Wv, const float* __restrict__ Wf,
    unsigned short* __restrict__ WT)
{
    const int z = blockIdx.z;
    if (z == 3 && blockIdx.x > 0) return;
    const float* W = (z == 0) ? Wq : (z == 1) ? Wk : (z == 2) ? Wv : Wf;
    const int ncol = (z == 3) ? 64 : DMODEL;
    unsigned short* out = WT + (size_t)z * DMODEL * DMODEL;

    __shared__ float Lt[64][65];
    const int tid = threadIdx.x;
    const int r0 = blockIdx.y * 64;
    const int c0 = blockIdx.x * 64;

    #pragma unroll
    for (int p = 0; p < 4; p++) {
        int row = (tid >> 4) + p * 16;
        int c4 = (tid & 15) * 4;
        float4 v = *(const float4*)(W + (size_t)(r0 + row) * ncol + c0 + c4);
        Lt[row][c4 + 0] = v.x; Lt[row][c4 + 1] = v.y;
        Lt[row][c4 + 2] = v.z; Lt[row][c4 + 3] = v.w;
    }
    __syncthreads();
    #pragma unroll
    for (int p = 0; p < 4; p++) {
        int nr = (tid >> 4) + p * 16;
        int kc = (tid & 15) * 4;
        unsigned short t[4];
        #pragma unroll
        for (int j = 0; j < 4; j++) t[j] = f2bf_rne(Lt[kc + j][nr]);
        *(uint2*)(out + (size_t)(c0 + nr) * DMODEL + r0 + kc) = *(uint2*)t;
    }
}

// ---------------------------------------------------------------------------
// Kernel 1: QKV projection, bf16 MFMA 16x16x32, BK=64.  launch_bounds(256,5)
// caps VGPR at 102 -> guarantees 5 blocks/CU residency (LDS allows 160/32=5),
// shrinking the 1536-block dispatch tail (1536/1280 vs 1536/1024 rounds).
// Q output pre-scaled by CK.  V stored transposed [d][s].
// ---------------------------------------------------------------------------
__global__ __launch_bounds__(256, 5) void qkv_gemm_mfma(
    const unsigned short* __restrict__ xb,
    const unsigned short* __restrict__ WT,
    const float* __restrict__ bq, const float* __restrict__ bk,
    const float* __restrict__ bv,
    unsigned short* __restrict__ Qb, unsigned short* __restrict__ Kb,
    unsigned short* __restrict__ Vtb)
{
    __shared__ __align__(16) unsigned short As[16 * 512];
    __shared__ __align__(16) unsigned short Bs[16 * 512];

    const int z = blockIdx.z;
    const unsigned short* Wz = WT + (size_t)z * DMODEL * DMODEL;
    const float* bias = (z == 0) ? bq : (z == 1) ? bk : bv;

    const int tid = threadIdx.x;
    const int lane = tid & 63, w = tid >> 6;
    const int quad = lane >> 4, l15 = lane & 15;
    const int wm = w & 1, wn = w >> 1;

    const int OC0 = blockIdx.x * 128;
    const int R0  = blockIdx.y * 128;

    const unsigned short* gA0 = Wz + (size_t)(OC0 + w * 16 + l15) * DMODEL + quad * 8;
    const unsigned short* gA1 = gA0 + (size_t)64 * DMODEL;
    const unsigned short* gB0 = xb + (size_t)(R0 + w * 16 + l15) * DMODEL + quad * 8;
    const unsigned short* gB1 = gB0 + (size_t)64 * DMODEL;

    f32x4 acc[4][4];
    #pragma unroll
    for (int i = 0; i < 4; i++)
        #pragma unroll
        for (int j = 0; j < 4; j++)
            #pragma unroll
            for (int c = 0; c < 4; c++) acc[i][j][c] = 0.f;

    for (int k0 = 0; k0 < DMODEL; k0 += 64) {
        __syncthreads();
        gld16(As + ((w + 0) * 2 + 0) * 512, gA0 + k0);
        gld16(As + ((w + 0) * 2 + 1) * 512, gA0 + k0 + 32);
        gld16(As + ((w + 4) * 2 + 0) * 512, gA1 + k0);
        gld16(As + ((w + 4) * 2 + 1) * 512, gA1 + k0 + 32);
        gld16(Bs + ((w + 0) * 2 + 0) * 512, gB0 + k0);
        gld16(Bs + ((w + 0) * 2 + 1) * 512, gB0 + k0 + 32);
        gld16(Bs + ((w + 4) * 2 + 0) * 512, gB1 + k0);
        gld16(Bs + ((w + 4) * 2 + 1) * 512, gB1 + k0 + 32);
        __syncthreads();

        #pragma unroll
        for (int sl = 0; sl < 2; sl++) {
            bf16x8 af[4], bfr[4];
            #pragma unroll
            for (int t = 0; t < 4; t++) {
                af[t]  = *(const bf16x8*)&As[((wm * 4 + t) * 2 + sl) * 512 + lane * 8];
                bfr[t] = *(const bf16x8*)&Bs[((wn * 4 + t) * 2 + sl) * 512 + lane * 8];
            }
            if (z != 2) {
                #pragma unroll
                for (int mt = 0; mt < 4; mt++)
                    #pragma unroll
                    for (int nt = 0; nt < 4; nt++)
                        acc[mt][nt] = __builtin_amdgcn_mfma_f32_16x16x32_bf16(
                            af[mt], bfr[nt], acc[mt][nt], 0, 0, 0);
            } else {
                #pragma unroll
                for (int mt = 0; mt < 4; mt++)
                    #pragma unroll
                    for (int nt = 0; nt < 4; nt++)
                        acc[mt][nt] = __builtin_amdgcn_mfma_f32_16x16x32_bf16(
                            bfr[nt], af[mt], acc[mt][nt], 0, 0, 0);
            }
        }
    }

    if (z != 2) {
        unsigned short* out = (z == 0) ? Qb : Kb;
        const float qs = (z == 0) ? CK : 1.0f;
        #pragma unroll
        for (int mt = 0; mt < 4; mt++) {
            int oc = OC0 + wm * 64 + mt * 16 + quad * 4;
            float4 bv4 = *(const float4*)&bias[oc];
            #pragma unroll
            for (int nt = 0; nt < 4; nt++) {
                int row = R0 + wn * 64 + nt * 16 + l15;
                unsigned short t4[4];
                t4[0] = f2bf_rne((acc[mt][nt][0] + bv4.x) * qs);
                t4[1] = f2bf_rne((acc[mt][nt][1] + bv4.y) * qs);
                t4[2] = f2bf_rne((acc[mt][nt][2] + bv4.z) * qs);
                t4[3] = f2bf_rne((acc[mt][nt][3] + bv4.w) * qs);
                *(uint2*)(out + (size_t)row * DMODEL + oc) = *(uint2*)t4;
            }
        }
    } else {
        const int b = R0 >> 11;
        const int sbase = (R0 & 2047) + wn * 64;
        #pragma unroll
        for (int mt = 0; mt < 4; mt++) {
            int oc = OC0 + wm * 64 + mt * 16 + l15;
            float bvv = bias[oc];
            #pragma unroll
            for (int nt = 0; nt < 4; nt++) {
                int s = sbase + nt * 16 + quad * 4;
                unsigned short t4[4];
                t4[0] = f2bf_rne(acc[mt][nt][0] + bvv);
                t4[1] = f2bf_rne(acc[mt][nt][1] + bvv);
                t4[2] = f2bf_rne(acc[mt][nt][2] + bvv);
                t4[3] = f2bf_rne(acc[mt][nt][3] + bvv);
                *(uint2*)(Vtb + (size_t)(b * DMODEL + oc) * S_LEN + s) = *(uint2*)t4;
            }
        }
    }
}

// ---------------------------------------------------------------------------
// Kernel 2: flash attention — EXACT R8 build (measured optimum: 256 thr,
// 32 q-rows/wave, 128-key stages, 40 KB LDS, 4 blocks/CU).  Perturbations
// measured worse: 64 rows/wave (R7), 16 rows/wave (R9), no-LDS (R6).
// No softmax max; l via MFMA-ones in O's C-layout; zero-C first MFMA.
// ---------------------------------------------------------------------------
__global__ __launch_bounds__(256, 4) void flash_attn_mfma(
    const unsigned short* __restrict__ Qg,   // [B*S,1024] bf16, pre-scaled by CK
    const unsigned short* __restrict__ Kg,   // [B*S,1024] bf16
    const unsigned short* __restrict__ Vtg,  // [B,H,64,S] bf16
    unsigned short* __restrict__ ctxb)       // [B*S,1024] bf16
{
    __shared__ __align__(16) unsigned short Ks[16 * 512];  // 16 KB
    __shared__ __align__(16) unsigned short Vs[16 * 512];  // 16 KB
    __shared__ __align__(16) unsigned short Ps[8 * 512];   //  8 KB

    const int tid  = threadIdx.x;
    const int lane = tid & 63, w = tid >> 6;
    const int quad = lane >> 4, l15 = lane & 15;
    const int b = blockIdx.z, h = blockIdx.y;
    const int r0 = blockIdx.x * 128;

    bf16x8 qf[2][2];
    #pragma unroll
    for (int nt = 0; nt < 2; nt++)
        #pragma unroll
        for (int ds = 0; ds < 2; ds++)
            qf[nt][ds] = *(const bf16x8*)(Qg +
                (size_t)(b * S_LEN + r0 + w * 32 + nt * 16 + l15) * DMODEL +
                h * HD + ds * 32 + quad * 8);

    const unsigned short* gK = Kg + (size_t)(b * S_LEN + w * 16 + l15) * DMODEL + h * HD + quad * 8;
    const unsigned short* gV = Vtg + ((size_t)((b * NH + h) * HD + w * 16 + l15)) * S_LEN + quad * 8;

    f32x4 O[2][4], lsum[2];
    #pragma unroll
    for (int rt = 0; rt < 2; rt++) {
        #pragma unroll
        for (int c = 0; c < 4; c++) lsum[rt][c] = 0.f;
        #pragma unroll
        for (int dt = 0; dt < 4; dt++)
            #pragma unroll
            for (int c = 0; c < 4; c++) O[rt][dt][c] = 0.f;
    }

    f32x4 zero4;
    #pragma unroll
    for (int c = 0; c < 4; c++) zero4[c] = 0.f;
    bf16x8 ones;
    #pragma unroll
    for (int c = 0; c < 8; c++) ones[c] = (short)0x3F80;   // bf16 1.0

    for (int st = 0; st < S_LEN / 128; st++) {
        __syncthreads();
        gld16(Ks + ((w + 0) * 2 + 0) * 512, gK);
        gld16(Ks + ((w + 0) * 2 + 1) * 512, gK + 32);
        gld16(Ks + ((w + 4) * 2 + 0) * 512, gK + (size_t)64 * DMODEL);
        gld16(Ks + ((w + 4) * 2 + 1) * 512, gK + (size_t)64 * DMODEL + 32);
        gld16(Vs + (w * 4 + 0) * 512, gV);
        gld16(Vs + (w * 4 + 1) * 512, gV + 32);
        gld16(Vs + (w * 4 + 2) * 512, gV + 64);
        gld16(Vs + (w * 4 + 3) * 512, gV + 96);
        gK += (size_t)128 * DMODEL;
        gV += 128;
        __syncthreads();

        #pragma unroll
        for (int r = 0; r < 4; r++) {
            f32x4 sc[2][2];
            {
                bf16x8 kf0 = *(const bf16x8*)&Ks[((r * 2 + 0) * 2 + 0) * 512 + lane * 8];
                bf16x8 kf1 = *(const bf16x8*)&Ks[((r * 2 + 1) * 2 + 0) * 512 + lane * 8];
                sc[0][0] = __builtin_amdgcn_mfma_f32_16x16x32_bf16(kf0, qf[0][0], zero4, 0, 0, 0);
                sc[0][1] = __builtin_amdgcn_mfma_f32_16x16x32_bf16(kf0, qf[1][0], zero4, 0, 0, 0);
                sc[1][0] = __builtin_amdgcn_mfma_f32_16x16x32_bf16(kf1, qf[0][0], zero4, 0, 0, 0);
                sc[1][1] = __builtin_amdgcn_mfma_f32_16x16x32_bf16(kf1, qf[1][0], zero4, 0, 0, 0);
                kf0 = *(const bf16x8*)&Ks[((r * 2 + 0) * 2 + 1) * 512 + lane * 8];
                kf1 = *(const bf16x8*)&Ks[((r * 2 + 1) * 2 + 1) * 512 + lane * 8];
                sc[0][0] = __builtin_amdgcn_mfma_f32_16x16x32_bf16(kf0, qf[0][1], sc[0][0], 0, 0, 0);
                sc[0][1] = __builtin_amdgcn_mfma_f32_16x16x32_bf16(kf0, qf[1][1], sc[0][1], 0, 0, 0);
                sc[1][0] = __builtin_amdgcn_mfma_f32_16x16x32_bf16(kf1, qf[0][1], sc[1][0], 0, 0, 0);
                sc[1][1] = __builtin_amdgcn_mfma_f32_16x16x32_bf16(kf1, qf[1][1], sc[1][1], 0, 0, 0);
            }

            #pragma unroll
            for (int nt = 0; nt < 2; nt++) {
                #pragma unroll
                for (int mt = 0; mt < 2; mt++) {
                    unsigned u[4];
                    #pragma unroll
                    for (int c = 0; c < 4; c++)
                        u[c] = __float_as_uint(exp2f(sc[mt][nt][c]));
                    uint2 pk;
                    pk.x = __builtin_amdgcn_perm(u[1], u[0], 0x07060302u);
                    pk.y = __builtin_amdgcn_perm(u[3], u[2], 0x07060302u);
                    int off = (w * 2 + nt) * 512 + (mt * 2 + (quad >> 1)) * 128 +
                              l15 * 8 + (quad & 1) * 4;
                    *(uint2*)&Ps[off] = pk;
                }
            }

            bf16x8 pf0 = *(const bf16x8*)&Ps[(w * 2 + 0) * 512 + lane * 8];
            bf16x8 pf1 = *(const bf16x8*)&Ps[(w * 2 + 1) * 512 + lane * 8];
            lsum[0] = __builtin_amdgcn_mfma_f32_16x16x32_bf16(pf0, ones, lsum[0], 0, 0, 0);
            lsum[1] = __builtin_amdgcn_mfma_f32_16x16x32_bf16(pf1, ones, lsum[1], 0, 0, 0);
            #pragma unroll
            for (int dt = 0; dt < 4; dt++) {
                bf16x8 vf = *(const bf16x8*)&Vs[(dt * 4 + r) * 512 + lane * 8];
                O[0][dt] = __builtin_amdgcn_mfma_f32_16x16x32_bf16(pf0, vf, O[0][dt], 0, 0, 0);
                O[1][dt] = __builtin_amdgcn_mfma_f32_16x16x32_bf16(pf1, vf, O[1][dt], 0, 0, 0);
            }
        }
    }

    const size_t srow = (size_t)(b * S_LEN + r0 + w * 32);
    #pragma unroll
    for (int rt = 0; rt < 2; rt++) {
        #pragma unroll
        for (int reg = 0; reg < 4; reg++) {
            float li = 1.0f / lsum[rt][reg];
            size_t rowoff = (srow + rt * 16 + quad * 4 + reg) * DMODEL + h * HD + l15;
            #pragma unroll
            for (int dt = 0; dt < 4; dt++)
                ctxb[rowoff + dt * 16] = f2bf_rne(O[rt][dt][reg] * li);
        }
    }
}

// ---------------------------------------------------------------------------
// Kernel 3: output projection v4, 8-way K-split.  512 blocks x 512 thr
// (16 waves/CU).  Block = 16 rows; wave w reduces K slice [w*128,(w+1)*128)
// (4 MFMA iters); partials combined via 32 KB LDS + one barrier.
// ---------------------------------------------------------------------------
__global__ __launch_bounds__(512) void out_proj_mfma(
    const unsigned short* __restrict__ ctxb,
    const unsigned short* __restrict__ WfT,
    const float* __restrict__ bfb,
    float* __restrict__ out)
{
    __shared__ float Red[8 * 1024];   // [wave][lane][j*4+reg], 32 KB

    const int tid = threadIdx.x;
    const int lane = tid & 63, w = tid >> 6;    // w 0..7
    const int quad = lane >> 4, l15 = lane & 15;
    const int m0 = blockIdx.x * 16;

    const unsigned short* pA = ctxb + (size_t)(m0 + l15) * DMODEL + w * 128 + quad * 8;
    const unsigned short* pB = WfT + (size_t)l15 * DMODEL + w * 128 + quad * 8;

    f32x4 acc[4];
    #pragma unroll
    for (int j = 0; j < 4; j++)
        #pragma unroll
        for (int c = 0; c < 4; c++) acc[j][c] = 0.f;

    #pragma unroll
    for (int k0 = 0; k0 < 128; k0 += 32) {
        bf16x8 af = *(const bf16x8*)(pA + k0);
        #pragma unroll
        for (int j = 0; j < 4; j++) {
            bf16x8 bfr = *(const bf16x8*)(pB + (size_t)j * 16 * DMODEL + k0);
            acc[j] = __builtin_amdgcn_mfma_f32_16x16x32_bf16(af, bfr, acc[j], 0, 0, 0);
        }
    }

    #pragma unroll
    for (int j = 0; j < 4; j++)
        #pragma unroll
        for (int reg = 0; reg < 4; reg++)
            Red[w * 1024 + lane * 16 + j * 4 + reg] = acc[j][reg];
    __syncthreads();

    // reducer: 512 thr -> 1024 outputs (2 adjacent cols each)
    const int row = tid >> 5;          // 0..15
    const int c0  = (tid & 31) * 2;    // 0..62
    float2 o;
    float* op = &o.x;
    #pragma unroll
    for (int cc = 0; cc < 2; cc++) {
        int col = c0 + cc;
        int idx = ((row >> 2) * 16 + (col & 15)) * 16 + (col >> 4) * 4 + (row & 3);
        float s = 0.f;
        #pragma unroll
        for (int wv = 0; wv < 8; wv++) s += Red[wv * 1024 + idx];
        op[cc] = s + bfb[col];
    }
    *(float2*)(out + (size_t)(m0 + row) * HD + c0) = o;
}

// ---------------------------------------------------------------------------
extern "C" void kernel_launch(void* const* d_in, const int* in_sizes, int n_in,
                              void* d_out, int out_size, void* d_ws, size_t ws_size,
                              hipStream_t stream)
{
    (void)in_sizes; (void)n_in; (void)out_size; (void)ws_size;
    const float* x  = (const float*)d_in[0];
    const float* Wq = (const float*)d_in[1];
    const float* bq = (const float*)d_in[2];
    const float* Wk = (const float*)d_in[3];
    const float* bk = (const float*)d_in[4];
    const float* Wv = (const float*)d_in[5];
    const float* bv = (const float*)d_in[6];
    const float* Wf = (const float*)d_in[7];
    const float* bf = (const float*)d_in[8];
    float* out = (float*)d_out;

    char* wsb = (char*)d_ws;
    unsigned short* xb   = (unsigned short*)wsb;            // 16 MB, dead after qkv
    unsigned short* ctxb = (unsigned short*)wsb;            // reuses xb region
    unsigned short* WT   = xb + (size_t)M_TOT * DMODEL;     // 3x2 MB + WfT
    unsigned short* WfT  = WT + (size_t)3 * DMODEL * DMODEL;
    unsigned short* Qb   = (unsigned short*)(wsb + (size_t)32 * 1024 * 1024);
    unsigned short* Kb   = Qb + (size_t)M_TOT * DMODEL;
    unsigned short* Vtb  = Kb + (size_t)M_TOT * DMODEL;

    cvt_x<<<dim3(M_TOT * DMODEL / 4 / 256), 256, 0, stream>>>(x, xb);
    cvt_wT<<<dim3(16, 16, 4), 256, 0, stream>>>(Wq, Wk, Wv, Wf, WT);
    qkv_gemm_mfma<<<dim3(8, 64, 3), 256, 0, stream>>>(xb, WT, bq, bk, bv, Qb, Kb, Vtb);
    flash_attn_mfma<<<dim3(S_LEN / 128, NH, BATCH), 256, 0, stream>>>(Qb, Kb, Vtb, ctxb);
    out_proj_mfma<<<dim3(M_TOT / 16), 512, 0, stream>>>(ctxb, WfT, bf, out);
}

// Round 11
// 313.508 us; speedup vs baseline: 2.8485x; 2.8485x over previous
//
#include <hip/hip_runtime.h>
#include <math.h>

#define S_LEN 2048
#define NH 16
#define HD 64
#define DMODEL 1024
#define BATCH 4
#define M_TOT (BATCH * S_LEN)   // 8192

typedef __attribute__((ext_vector_type(8))) short bf16x8;
typedef __attribute__((ext_vector_type(4))) float f32x4;

#define CK 0.18033688f   // (1/sqrt(64)) * log2(e), folded into Q at projection

__device__ __forceinline__ unsigned short f2bf_rne(float f) {
    unsigned u = __float_as_uint(f);
    u += 0x7fffu + ((u >> 16) & 1u);
    return (unsigned short)(u >> 16);
}

__device__ __forceinline__ void gld16(unsigned short* lds, const unsigned short* g) {
    __builtin_amdgcn_global_load_lds(
        (const __attribute__((address_space(1))) void*)g,
        (__attribute__((address_space(3))) void*)lds, 16, 0, 0);
}

// ---------------------------------------------------------------------------
// cvt_x: fp32 -> bf16, x [8192,1024]
// ---------------------------------------------------------------------------
__global__ __launch_bounds__(256) void cvt_x(
    const float* __restrict__ x, unsigned short* __restrict__ xb)
{
    size_t i = ((size_t)blockIdx.x * 256 + threadIdx.x) * 4;
    float4 v = *(const float4*)(x + i);
    unsigned short t[4];
    t[0] = f2bf_rne(v.x); t[1] = f2bf_rne(v.y);
    t[2] = f2bf_rne(v.z); t[3] = f2bf_rne(v.w);
    *(uint2*)(xb + i) = *(uint2*)t;
}

// ---------------------------------------------------------------------------
// cvt_wT: transpose + convert W [k][n] fp32 -> WT [n][k=1024] bf16.
// z=0..2: Wq/Wk/Wv (1024x1024).  z=3: Wf (1024x64) -> WfT [64][1024].
// ---------------------------------------------------------------------------
__global__ __launch_bounds__(256) void cvt_wT(
    const float* __restrict__ Wq, const float* __restrict__ Wk,
    const float* __restrict__ Wv, const float* __restrict__ Wf,
    unsigned short* __restrict__ WT)
{
    const int z = blockIdx.z;
    if (z == 3 && blockIdx.x > 0) return;
    const float* W = (z == 0) ? Wq : (z == 1) ? Wk : (z == 2) ? Wv : Wf;
    const int ncol = (z == 3) ? 64 : DMODEL;
    unsigned short* out = WT + (size_t)z * DMODEL * DMODEL;

    __shared__ float Lt[64][65];
    const int tid = threadIdx.x;
    const int r0 = blockIdx.y * 64;
    const int c0 = blockIdx.x * 64;

    #pragma unroll
    for (int p = 0; p < 4; p++) {
        int row = (tid >> 4) + p * 16;
        int c4 = (tid & 15) * 4;
        float4 v = *(const float4*)(W + (size_t)(r0 + row) * ncol + c0 + c4);
        Lt[row][c4 + 0] = v.x; Lt[row][c4 + 1] = v.y;
        Lt[row][c4 + 2] = v.z; Lt[row][c4 + 3] = v.w;
    }
    __syncthreads();
    #pragma unroll
    for (int p = 0; p < 4; p++) {
        int nr = (tid >> 4) + p * 16;
        int kc = (tid & 15) * 4;
        unsigned short t[4];
        #pragma unroll
        for (int j = 0; j < 4; j++) t[j] = f2bf_rne(Lt[kc + j][nr]);
        *(uint2*)(out + (size_t)(c0 + nr) * DMODEL + r0 + kc) = *(uint2*)t;
    }
}

// ---------------------------------------------------------------------------
// Kernel 1: QKV projection, bf16 MFMA 16x16x32, BK=64 — EXACT R8 build.
// NOTE: do NOT add a min-waves launch_bounds here: R10's (256,5) capped
// VGPR at 48 < the 64-reg accumulator -> scratch spill, 3.26 GB traffic, 6x
// slowdown.  Q output pre-scaled by CK.  V stored transposed [d][s].
// ---------------------------------------------------------------------------
__global__ __launch_bounds__(256) void qkv_gemm_mfma(
    const unsigned short* __restrict__ xb,
    const unsigned short* __restrict__ WT,
    const float* __restrict__ bq, const float* __restrict__ bk,
    const float* __restrict__ bv,
    unsigned short* __restrict__ Qb, unsigned short* __restrict__ Kb,
    unsigned short* __restrict__ Vtb)
{
    __shared__ __align__(16) unsigned short As[16 * 512];
    __shared__ __align__(16) unsigned short Bs[16 * 512];

    const int z = blockIdx.z;
    const unsigned short* Wz = WT + (size_t)z * DMODEL * DMODEL;
    const float* bias = (z == 0) ? bq : (z == 1) ? bk : bv;

    const int tid = threadIdx.x;
    const int lane = tid & 63, w = tid >> 6;
    const int quad = lane >> 4, l15 = lane & 15;
    const int wm = w & 1, wn = w >> 1;

    const int OC0 = blockIdx.x * 128;
    const int R0  = blockIdx.y * 128;

    const unsigned short* gA0 = Wz + (size_t)(OC0 + w * 16 + l15) * DMODEL + quad * 8;
    const unsigned short* gA1 = gA0 + (size_t)64 * DMODEL;
    const unsigned short* gB0 = xb + (size_t)(R0 + w * 16 + l15) * DMODEL + quad * 8;
    const unsigned short* gB1 = gB0 + (size_t)64 * DMODEL;

    f32x4 acc[4][4];
    #pragma unroll
    for (int i = 0; i < 4; i++)
        #pragma unroll
        for (int j = 0; j < 4; j++)
            #pragma unroll
            for (int c = 0; c < 4; c++) acc[i][j][c] = 0.f;

    for (int k0 = 0; k0 < DMODEL; k0 += 64) {
        __syncthreads();
        gld16(As + ((w + 0) * 2 + 0) * 512, gA0 + k0);
        gld16(As + ((w + 0) * 2 + 1) * 512, gA0 + k0 + 32);
        gld16(As + ((w + 4) * 2 + 0) * 512, gA1 + k0);
        gld16(As + ((w + 4) * 2 + 1) * 512, gA1 + k0 + 32);
        gld16(Bs + ((w + 0) * 2 + 0) * 512, gB0 + k0);
        gld16(Bs + ((w + 0) * 2 + 1) * 512, gB0 + k0 + 32);
        gld16(Bs + ((w + 4) * 2 + 0) * 512, gB1 + k0);
        gld16(Bs + ((w + 4) * 2 + 1) * 512, gB1 + k0 + 32);
        __syncthreads();

        #pragma unroll
        for (int sl = 0; sl < 2; sl++) {
            bf16x8 af[4], bfr[4];
            #pragma unroll
            for (int t = 0; t < 4; t++) {
                af[t]  = *(const bf16x8*)&As[((wm * 4 + t) * 2 + sl) * 512 + lane * 8];
                bfr[t] = *(const bf16x8*)&Bs[((wn * 4 + t) * 2 + sl) * 512 + lane * 8];
            }
            if (z != 2) {
                #pragma unroll
                for (int mt = 0; mt < 4; mt++)
                    #pragma unroll
                    for (int nt = 0; nt < 4; nt++)
                        acc[mt][nt] = __builtin_amdgcn_mfma_f32_16x16x32_bf16(
                            af[mt], bfr[nt], acc[mt][nt], 0, 0, 0);
            } else {
                #pragma unroll
                for (int mt = 0; mt < 4; mt++)
                    #pragma unroll
                    for (int nt = 0; nt < 4; nt++)
                        acc[mt][nt] = __builtin_amdgcn_mfma_f32_16x16x32_bf16(
                            bfr[nt], af[mt], acc[mt][nt], 0, 0, 0);
            }
        }
    }

    if (z != 2) {
        unsigned short* out = (z == 0) ? Qb : Kb;
        const float qs = (z == 0) ? CK : 1.0f;
        #pragma unroll
        for (int mt = 0; mt < 4; mt++) {
            int oc = OC0 + wm * 64 + mt * 16 + quad * 4;
            float4 bv4 = *(const float4*)&bias[oc];
            #pragma unroll
            for (int nt = 0; nt < 4; nt++) {
                int row = R0 + wn * 64 + nt * 16 + l15;
                unsigned short t4[4];
                t4[0] = f2bf_rne((acc[mt][nt][0] + bv4.x) * qs);
                t4[1] = f2bf_rne((acc[mt][nt][1] + bv4.y) * qs);
                t4[2] = f2bf_rne((acc[mt][nt][2] + bv4.z) * qs);
                t4[3] = f2bf_rne((acc[mt][nt][3] + bv4.w) * qs);
                *(uint2*)(out + (size_t)row * DMODEL + oc) = *(uint2*)t4;
            }
        }
    } else {
        const int b = R0 >> 11;
        const int sbase = (R0 & 2047) + wn * 64;
        #pragma unroll
        for (int mt = 0; mt < 4; mt++) {
            int oc = OC0 + wm * 64 + mt * 16 + l15;
            float bvv = bias[oc];
            #pragma unroll
            for (int nt = 0; nt < 4; nt++) {
                int s = sbase + nt * 16 + quad * 4;
                unsigned short t4[4];
                t4[0] = f2bf_rne(acc[mt][nt][0] + bvv);
                t4[1] = f2bf_rne(acc[mt][nt][1] + bvv);
                t4[2] = f2bf_rne(acc[mt][nt][2] + bvv);
                t4[3] = f2bf_rne(acc[mt][nt][3] + bvv);
                *(uint2*)(Vtb + (size_t)(b * DMODEL + oc) * S_LEN + s) = *(uint2*)t4;
            }
        }
    }
}

// ---------------------------------------------------------------------------
// Kernel 2: flash attention — EXACT R8 build (measured optimum: 256 thr,
// 32 q-rows/wave, 128-key stages, 40 KB LDS, 4 blocks/CU).  Perturbations
// measured worse: 64 rows/wave (R7), 16 rows/wave (R9), no-LDS (R6).
// ---------------------------------------------------------------------------
__global__ __launch_bounds__(256, 4) void flash_attn_mfma(
    const unsigned short* __restrict__ Qg,   // [B*S,1024] bf16, pre-scaled by CK
    const unsigned short* __restrict__ Kg,   // [B*S,1024] bf16
    const unsigned short* __restrict__ Vtg,  // [B,H,64,S] bf16
    unsigned short* __restrict__ ctxb)       // [B*S,1024] bf16
{
    __shared__ __align__(16) unsigned short Ks[16 * 512];  // 16 KB
    __shared__ __align__(16) unsigned short Vs[16 * 512];  // 16 KB
    __shared__ __align__(16) unsigned short Ps[8 * 512];   //  8 KB

    const int tid  = threadIdx.x;
    const int lane = tid & 63, w = tid >> 6;
    const int quad = lane >> 4, l15 = lane & 15;
    const int b = blockIdx.z, h = blockIdx.y;
    const int r0 = blockIdx.x * 128;

    bf16x8 qf[2][2];
    #pragma unroll
    for (int nt = 0; nt < 2; nt++)
        #pragma unroll
        for (int ds = 0; ds < 2; ds++)
            qf[nt][ds] = *(const bf16x8*)(Qg +
                (size_t)(b * S_LEN + r0 + w * 32 + nt * 16 + l15) * DMODEL +
                h * HD + ds * 32 + quad * 8);

    const unsigned short* gK = Kg + (size_t)(b * S_LEN + w * 16 + l15) * DMODEL + h * HD + quad * 8;
    const unsigned short* gV = Vtg + ((size_t)((b * NH + h) * HD + w * 16 + l15)) * S_LEN + quad * 8;

    f32x4 O[2][4], lsum[2];
    #pragma unroll
    for (int rt = 0; rt < 2; rt++) {
        #pragma unroll
        for (int c = 0; c < 4; c++) lsum[rt][c] = 0.f;
        #pragma unroll
        for (int dt = 0; dt < 4; dt++)
            #pragma unroll
            for (int c = 0; c < 4; c++) O[rt][dt][c] = 0.f;
    }

    f32x4 zero4;
    #pragma unroll
    for (int c = 0; c < 4; c++) zero4[c] = 0.f;
    bf16x8 ones;
    #pragma unroll
    for (int c = 0; c < 8; c++) ones[c] = (short)0x3F80;   // bf16 1.0

    for (int st = 0; st < S_LEN / 128; st++) {
        __syncthreads();
        gld16(Ks + ((w + 0) * 2 + 0) * 512, gK);
        gld16(Ks + ((w + 0) * 2 + 1) * 512, gK + 32);
        gld16(Ks + ((w + 4) * 2 + 0) * 512, gK + (size_t)64 * DMODEL);
        gld16(Ks + ((w + 4) * 2 + 1) * 512, gK + (size_t)64 * DMODEL + 32);
        gld16(Vs + (w * 4 + 0) * 512, gV);
        gld16(Vs + (w * 4 + 1) * 512, gV + 32);
        gld16(Vs + (w * 4 + 2) * 512, gV + 64);
        gld16(Vs + (w * 4 + 3) * 512, gV + 96);
        gK += (size_t)128 * DMODEL;
        gV += 128;
        __syncthreads();

        #pragma unroll
        for (int r = 0; r < 4; r++) {
            f32x4 sc[2][2];
            {
                bf16x8 kf0 = *(const bf16x8*)&Ks[((r * 2 + 0) * 2 + 0) * 512 + lane * 8];
                bf16x8 kf1 = *(const bf16x8*)&Ks[((r * 2 + 1) * 2 + 0) * 512 + lane * 8];
                sc[0][0] = __builtin_amdgcn_mfma_f32_16x16x32_bf16(kf0, qf[0][0], zero4, 0, 0, 0);
                sc[0][1] = __builtin_amdgcn_mfma_f32_16x16x32_bf16(kf0, qf[1][0], zero4, 0, 0, 0);
                sc[1][0] = __builtin_amdgcn_mfma_f32_16x16x32_bf16(kf1, qf[0][0], zero4, 0, 0, 0);
                sc[1][1] = __builtin_amdgcn_mfma_f32_16x16x32_bf16(kf1, qf[1][0], zero4, 0, 0, 0);
                kf0 = *(const bf16x8*)&Ks[((r * 2 + 0) * 2 + 1) * 512 + lane * 8];
                kf1 = *(const bf16x8*)&Ks[((r * 2 + 1) * 2 + 1) * 512 + lane * 8];
                sc[0][0] = __builtin_amdgcn_mfma_f32_16x16x32_bf16(kf0, qf[0][1], sc[0][0], 0, 0, 0);
                sc[0][1] = __builtin_amdgcn_mfma_f32_16x16x32_bf16(kf0, qf[1][1], sc[0][1], 0, 0, 0);
                sc[1][0] = __builtin_amdgcn_mfma_f32_16x16x32_bf16(kf1, qf[0][1], sc[1][0], 0, 0, 0);
                sc[1][1] = __builtin_amdgcn_mfma_f32_16x16x32_bf16(kf1, qf[1][1], sc[1][1], 0, 0, 0);
            }

            #pragma unroll
            for (int nt = 0; nt < 2; nt++) {
                #pragma unroll
                for (int mt = 0; mt < 2; mt++) {
                    unsigned u[4];
                    #pragma unroll
                    for (int c = 0; c < 4; c++)
                        u[c] = __float_as_uint(exp2f(sc[mt][nt][c]));
                    uint2 pk;
                    pk.x = __builtin_amdgcn_perm(u[1], u[0], 0x07060302u);
                    pk.y = __builtin_amdgcn_perm(u[3], u[2], 0x07060302u);
                    int off = (w * 2 + nt) * 512 + (mt * 2 + (quad >> 1)) * 128 +
                              l15 * 8 + (quad & 1) * 4;
                    *(uint2*)&Ps[off] = pk;
                }
            }

            bf16x8 pf0 = *(const bf16x8*)&Ps[(w * 2 + 0) * 512 + lane * 8];
            bf16x8 pf1 = *(const bf16x8*)&Ps[(w * 2 + 1) * 512 + lane * 8];
            lsum[0] = __builtin_amdgcn_mfma_f32_16x16x32_bf16(pf0, ones, lsum[0], 0, 0, 0);
            lsum[1] = __builtin_amdgcn_mfma_f32_16x16x32_bf16(pf1, ones, lsum[1], 0, 0, 0);
            #pragma unroll
            for (int dt = 0; dt < 4; dt++) {
                bf16x8 vf = *(const bf16x8*)&Vs[(dt * 4 + r) * 512 + lane * 8];
                O[0][dt] = __builtin_amdgcn_mfma_f32_16x16x32_bf16(pf0, vf, O[0][dt], 0, 0, 0);
                O[1][dt] = __builtin_amdgcn_mfma_f32_16x16x32_bf16(pf1, vf, O[1][dt], 0, 0, 0);
            }
        }
    }

    const size_t srow = (size_t)(b * S_LEN + r0 + w * 32);
    #pragma unroll
    for (int rt = 0; rt < 2; rt++) {
        #pragma unroll
        for (int reg = 0; reg < 4; reg++) {
            float li = 1.0f / lsum[rt][reg];
            size_t rowoff = (srow + rt * 16 + quad * 4 + reg) * DMODEL + h * HD + l15;
            #pragma unroll
            for (int dt = 0; dt < 4; dt++)
                ctxb[rowoff + dt * 16] = f2bf_rne(O[rt][dt][reg] * li);
        }
    }
}

// ---------------------------------------------------------------------------
// Kernel 3: output projection v4, 8-way K-split.  512 blocks x 512 thr
// (16 waves/CU).  Block = 16 rows; wave w reduces K slice [w*128,(w+1)*128)
// (4 MFMA iters); partials combined via 32 KB LDS + one barrier.
// ---------------------------------------------------------------------------
__global__ __launch_bounds__(512) void out_proj_mfma(
    const unsigned short* __restrict__ ctxb,
    const unsigned short* __restrict__ WfT,
    const float* __restrict__ bfb,
    float* __restrict__ out)
{
    __shared__ float Red[8 * 1024];   // [wave][lane][j*4+reg], 32 KB

    const int tid = threadIdx.x;
    const int lane = tid & 63, w = tid >> 6;    // w 0..7
    const int quad = lane >> 4, l15 = lane & 15;
    const int m0 = blockIdx.x * 16;

    const unsigned short* pA = ctxb + (size_t)(m0 + l15) * DMODEL + w * 128 + quad * 8;
    const unsigned short* pB = WfT + (size_t)l15 * DMODEL + w * 128 + quad * 8;

    f32x4 acc[4];
    #pragma unroll
    for (int j = 0; j < 4; j++)
        #pragma unroll
        for (int c = 0; c < 4; c++) acc[j][c] = 0.f;

    #pragma unroll
    for (int k0 = 0; k0 < 128; k0 += 32) {
        bf16x8 af = *(const bf16x8*)(pA + k0);
        #pragma unroll
        for (int j = 0; j < 4; j++) {
            bf16x8 bfr = *(const bf16x8*)(pB + (size_t)j * 16 * DMODEL + k0);
            acc[j] = __builtin_amdgcn_mfma_f32_16x16x32_bf16(af, bfr, acc[j], 0, 0, 0);
        }
    }

    #pragma unroll
    for (int j = 0; j < 4; j++)
        #pragma unroll
        for (int reg = 0; reg < 4; reg++)
            Red[w * 1024 + lane * 16 + j * 4 + reg] = acc[j][reg];
    __syncthreads();

    // reducer: 512 thr -> 1024 outputs (2 adjacent cols each)
    const int row = tid >> 5;          // 0..15
    const int c0  = (tid & 31) * 2;    // 0..62
    float2 o;
    float* op = &o.x;
    #pragma unroll
    for (int cc = 0; cc < 2; cc++) {
        int col = c0 + cc;
        int idx = ((row >> 2) * 16 + (col & 15)) * 16 + (col >> 4) * 4 + (row & 3);
        float s = 0.f;
        #pragma unroll
        for (int wv = 0; wv < 8; wv++) s += Red[wv * 1024 + idx];
        op[cc] = s + bfb[col];
    }
    *(float2*)(out + (size_t)(m0 + row) * HD + c0) = o;
}

// ---------------------------------------------------------------------------
extern "C" void kernel_launch(void* const* d_in, const int* in_sizes, int n_in,
                              void* d_out, int out_size, void* d_ws, size_t ws_size,
                              hipStream_t stream)
{
    (void)in_sizes; (void)n_in; (void)out_size; (void)ws_size;
    const float* x  = (const float*)d_in[0];
    const float* Wq = (const float*)d_in[1];
    const float* bq = (const float*)d_in[2];
    const float* Wk = (const float*)d_in[3];
    const float* bk = (const float*)d_in[4];
    const float* Wv = (const float*)d_in[5];
    const float* bv = (const float*)d_in[6];
    const float* Wf = (const float*)d_in[7];
    const float* bf = (const float*)d_in[8];
    float* out = (float*)d_out;

    char* wsb = (char*)d_ws;
    unsigned short* xb   = (unsigned short*)wsb;            // 16 MB, dead after qkv
    unsigned short* ctxb = (unsigned short*)wsb;            // reuses xb region
    unsigned short* WT   = xb + (size_t)M_TOT * DMODEL;     // 3x2 MB + WfT
    unsigned short* WfT  = WT + (size_t)3 * DMODEL * DMODEL;
    unsigned short* Qb   = (unsigned short*)(wsb + (size_t)32 * 1024 * 1024);
    unsigned short* Kb   = Qb + (size_t)M_TOT * DMODEL;
    unsigned short* Vtb  = Kb + (size_t)M_TOT * DMODEL;

    cvt_x<<<dim3(M_TOT * DMODEL / 4 / 256), 256, 0, stream>>>(x, xb);
    cvt_wT<<<dim3(16, 16, 4), 256, 0, stream>>>(Wq, Wk, Wv, Wf, WT);
    qkv_gemm_mfma<<<dim3(8, 64, 3), 256, 0, stream>>>(xb, WT, bq, bk, bv, Qb, Kb, Vtb);
    flash_attn_mfma<<<dim3(S_LEN / 128, NH, BATCH), 256, 0, stream>>>(Qb, Kb, Vtb, ctxb);
    out_proj_mfma<<<dim3(M_TOT / 16), 512, 0, stream>>>(ctxb, WfT, bf, out);
}

// Round 12
// 290.517 us; speedup vs baseline: 3.0739x; 1.0791x over previous
//
#include <hip/hip_runtime.h>
#include <math.h>

#define S_LEN 2048
#define NH 16
#define HD 64
#define DMODEL 1024
#define BATCH 4
#define M_TOT (BATCH * S_LEN)   // 8192

typedef __attribute__((ext_vector_type(8))) short bf16x8;
typedef __attribute__((ext_vector_type(4))) float f32x4;

#define CK 0.18033688f   // (1/sqrt(64)) * log2(e), folded into Q at projection

__device__ __forceinline__ unsigned short f2bf_rne(float f) {
    unsigned u = __float_as_uint(f);
    u += 0x7fffu + ((u >> 16) & 1u);
    return (unsigned short)(u >> 16);
}

__device__ __forceinline__ void gld16(unsigned short* lds, const unsigned short* g) {
    __builtin_amdgcn_global_load_lds(
        (const __attribute__((address_space(1))) void*)g,
        (__attribute__((address_space(3))) void*)lds, 16, 0, 0);
}

// ---------------------------------------------------------------------------
// cvt_fused: one dispatch for all input conversion.
// z=0..2: Wq/Wk/Wv [k][n] fp32 -> WT [n][k] bf16 (64x64 transpose tiles)
// z=3:    Wf (1024x64) -> WfT [64][1024]   (only blockIdx.x==0 active)
// z=4:    x fp32 -> bf16 (grid-strided, 256 blocks x 32 float4/thread)
// ---------------------------------------------------------------------------
__global__ __launch_bounds__(256) void cvt_fused(
    const float* __restrict__ x,
    const float* __restrict__ Wq, const float* __restrict__ Wk,
    const float* __restrict__ Wv, const float* __restrict__ Wf,
    unsigned short* __restrict__ xb, unsigned short* __restrict__ WT)
{
    const int z = blockIdx.z;
    const int tid = threadIdx.x;

    if (z < 4) {
        if (z == 3 && blockIdx.x > 0) return;
        const float* W = (z == 0) ? Wq : (z == 1) ? Wk : (z == 2) ? Wv : Wf;
        const int ncol = (z == 3) ? 64 : DMODEL;
        unsigned short* out = WT + (size_t)z * DMODEL * DMODEL;

        __shared__ float Lt[64][65];
        const int r0 = blockIdx.y * 64;
        const int c0 = blockIdx.x * 64;

        #pragma unroll
        for (int p = 0; p < 4; p++) {
            int row = (tid >> 4) + p * 16;
            int c4 = (tid & 15) * 4;
            float4 v = *(const float4*)(W + (size_t)(r0 + row) * ncol + c0 + c4);
            Lt[row][c4 + 0] = v.x; Lt[row][c4 + 1] = v.y;
            Lt[row][c4 + 2] = v.z; Lt[row][c4 + 3] = v.w;
        }
        __syncthreads();
        #pragma unroll
        for (int p = 0; p < 4; p++) {
            int nr = (tid >> 4) + p * 16;
            int kc = (tid & 15) * 4;
            unsigned short t[4];
            #pragma unroll
            for (int j = 0; j < 4; j++) t[j] = f2bf_rne(Lt[kc + j][nr]);
            *(uint2*)(out + (size_t)(c0 + nr) * DMODEL + r0 + kc) = *(uint2*)t;
        }
    } else {
        // x convert: 8192*1024 = 8,388,608 elems = 2,097,152 float4.
        // 256 blocks (by*16+bx) * 256 thr = 65536 threads, 32 float4 each.
        const int gtid = (blockIdx.y * 16 + blockIdx.x) * 256 + tid;
        #pragma unroll
        for (int it = 0; it < 8; it++) {
            #pragma unroll
            for (int k = 0; k < 4; k++) {
                size_t i = ((size_t)((it * 4 + k) * 65536) + gtid) * 4;
                float4 v = *(const float4*)(x + i);
                unsigned short t[4];
                t[0] = f2bf_rne(v.x); t[1] = f2bf_rne(v.y);
                t[2] = f2bf_rne(v.z); t[3] = f2bf_rne(v.w);
                *(uint2*)(xb + i) = *(uint2*)t;
            }
        }
    }
}

// ---------------------------------------------------------------------------
// Kernel 1: QKV projection, bf16 MFMA 16x16x32, BK=64 — EXACT R8 build.
// NOTE: do NOT add a min-waves launch_bounds here: R10's (256,5) capped
// VGPR at 48 < the 64-reg accumulator -> scratch spill, 3.26 GB traffic, 6x
// slowdown.  Q output pre-scaled by CK.  V stored transposed [d][s].
// ---------------------------------------------------------------------------
__global__ __launch_bounds__(256) void qkv_gemm_mfma(
    const unsigned short* __restrict__ xb,
    const unsigned short* __restrict__ WT,
    const float* __restrict__ bq, const float* __restrict__ bk,
    const float* __restrict__ bv,
    unsigned short* __restrict__ Qb, unsigned short* __restrict__ Kb,
    unsigned short* __restrict__ Vtb)
{
    __shared__ __align__(16) unsigned short As[16 * 512];
    __shared__ __align__(16) unsigned short Bs[16 * 512];

    const int z = blockIdx.z;
    const unsigned short* Wz = WT + (size_t)z * DMODEL * DMODEL;
    const float* bias = (z == 0) ? bq : (z == 1) ? bk : bv;

    const int tid = threadIdx.x;
    const int lane = tid & 63, w = tid >> 6;
    const int quad = lane >> 4, l15 = lane & 15;
    const int wm = w & 1, wn = w >> 1;

    const int OC0 = blockIdx.x * 128;
    const int R0  = blockIdx.y * 128;

    const unsigned short* gA0 = Wz + (size_t)(OC0 + w * 16 + l15) * DMODEL + quad * 8;
    const unsigned short* gA1 = gA0 + (size_t)64 * DMODEL;
    const unsigned short* gB0 = xb + (size_t)(R0 + w * 16 + l15) * DMODEL + quad * 8;
    const unsigned short* gB1 = gB0 + (size_t)64 * DMODEL;

    f32x4 acc[4][4];
    #pragma unroll
    for (int i = 0; i < 4; i++)
        #pragma unroll
        for (int j = 0; j < 4; j++)
            #pragma unroll
            for (int c = 0; c < 4; c++) acc[i][j][c] = 0.f;

    for (int k0 = 0; k0 < DMODEL; k0 += 64) {
        __syncthreads();
        gld16(As + ((w + 0) * 2 + 0) * 512, gA0 + k0);
        gld16(As + ((w + 0) * 2 + 1) * 512, gA0 + k0 + 32);
        gld16(As + ((w + 4) * 2 + 0) * 512, gA1 + k0);
        gld16(As + ((w + 4) * 2 + 1) * 512, gA1 + k0 + 32);
        gld16(Bs + ((w + 0) * 2 + 0) * 512, gB0 + k0);
        gld16(Bs + ((w + 0) * 2 + 1) * 512, gB0 + k0 + 32);
        gld16(Bs + ((w + 4) * 2 + 0) * 512, gB1 + k0);
        gld16(Bs + ((w + 4) * 2 + 1) * 512, gB1 + k0 + 32);
        __syncthreads();

        #pragma unroll
        for (int sl = 0; sl < 2; sl++) {
            bf16x8 af[4], bfr[4];
            #pragma unroll
            for (int t = 0; t < 4; t++) {
                af[t]  = *(const bf16x8*)&As[((wm * 4 + t) * 2 + sl) * 512 + lane * 8];
                bfr[t] = *(const bf16x8*)&Bs[((wn * 4 + t) * 2 + sl) * 512 + lane * 8];
            }
            if (z != 2) {
                #pragma unroll
                for (int mt = 0; mt < 4; mt++)
                    #pragma unroll
                    for (int nt = 0; nt < 4; nt++)
                        acc[mt][nt] = __builtin_amdgcn_mfma_f32_16x16x32_bf16(
                            af[mt], bfr[nt], acc[mt][nt], 0, 0, 0);
            } else {
                #pragma unroll
                for (int mt = 0; mt < 4; mt++)
                    #pragma unroll
                    for (int nt = 0; nt < 4; nt++)
                        acc[mt][nt] = __builtin_amdgcn_mfma_f32_16x16x32_bf16(
                            bfr[nt], af[mt], acc[mt][nt], 0, 0, 0);
            }
        }
    }

    if (z != 2) {
        unsigned short* out = (z == 0) ? Qb : Kb;
        const float qs = (z == 0) ? CK : 1.0f;
        #pragma unroll
        for (int mt = 0; mt < 4; mt++) {
            int oc = OC0 + wm * 64 + mt * 16 + quad * 4;
            float4 bv4 = *(const float4*)&bias[oc];
            #pragma unroll
            for (int nt = 0; nt < 4; nt++) {
                int row = R0 + wn * 64 + nt * 16 + l15;
                unsigned short t4[4];
                t4[0] = f2bf_rne((acc[mt][nt][0] + bv4.x) * qs);
                t4[1] = f2bf_rne((acc[mt][nt][1] + bv4.y) * qs);
                t4[2] = f2bf_rne((acc[mt][nt][2] + bv4.z) * qs);
                t4[3] = f2bf_rne((acc[mt][nt][3] + bv4.w) * qs);
                *(uint2*)(out + (size_t)row * DMODEL + oc) = *(uint2*)t4;
            }
        }
    } else {
        const int b = R0 >> 11;
        const int sbase = (R0 & 2047) + wn * 64;
        #pragma unroll
        for (int mt = 0; mt < 4; mt++) {
            int oc = OC0 + wm * 64 + mt * 16 + l15;
            float bvv = bias[oc];
            #pragma unroll
            for (int nt = 0; nt < 4; nt++) {
                int s = sbase + nt * 16 + quad * 4;
                unsigned short t4[4];
                t4[0] = f2bf_rne(acc[mt][nt][0] + bvv);
                t4[1] = f2bf_rne(acc[mt][nt][1] + bvv);
                t4[2] = f2bf_rne(acc[mt][nt][2] + bvv);
                t4[3] = f2bf_rne(acc[mt][nt][3] + bvv);
                *(uint2*)(Vtb + (size_t)(b * DMODEL + oc) * S_LEN + s) = *(uint2*)t4;
            }
        }
    }
}

// ---------------------------------------------------------------------------
// Kernel 2: flash attention — R8 structure (measured optimum: 256 thr,
// 32 q-rows/wave, 128-key stages, 40 KB LDS, 4 blocks/CU).  Perturbations
// measured worse: 64 rows/wave (R7), 16 rows/wave (R9), no-LDS (R6).
// Only change vs R11: exp2f -> __builtin_amdgcn_exp2f (bare v_exp_f32,
// bit-identical for |sc| << 126).
// ---------------------------------------------------------------------------
__global__ __launch_bounds__(256, 4) void flash_attn_mfma(
    const unsigned short* __restrict__ Qg,   // [B*S,1024] bf16, pre-scaled by CK
    const unsigned short* __restrict__ Kg,   // [B*S,1024] bf16
    const unsigned short* __restrict__ Vtg,  // [B,H,64,S] bf16
    unsigned short* __restrict__ ctxb)       // [B*S,1024] bf16
{
    __shared__ __align__(16) unsigned short Ks[16 * 512];  // 16 KB
    __shared__ __align__(16) unsigned short Vs[16 * 512];  // 16 KB
    __shared__ __align__(16) unsigned short Ps[8 * 512];   //  8 KB

    const int tid  = threadIdx.x;
    const int lane = tid & 63, w = tid >> 6;
    const int quad = lane >> 4, l15 = lane & 15;
    const int b = blockIdx.z, h = blockIdx.y;
    const int r0 = blockIdx.x * 128;

    bf16x8 qf[2][2];
    #pragma unroll
    for (int nt = 0; nt < 2; nt++)
        #pragma unroll
        for (int ds = 0; ds < 2; ds++)
            qf[nt][ds] = *(const bf16x8*)(Qg +
                (size_t)(b * S_LEN + r0 + w * 32 + nt * 16 + l15) * DMODEL +
                h * HD + ds * 32 + quad * 8);

    const unsigned short* gK = Kg + (size_t)(b * S_LEN + w * 16 + l15) * DMODEL + h * HD + quad * 8;
    const unsigned short* gV = Vtg + ((size_t)((b * NH + h) * HD + w * 16 + l15)) * S_LEN + quad * 8;

    f32x4 O[2][4], lsum[2];
    #pragma unroll
    for (int rt = 0; rt < 2; rt++) {
        #pragma unroll
        for (int c = 0; c < 4; c++) lsum[rt][c] = 0.f;
        #pragma unroll
        for (int dt = 0; dt < 4; dt++)
            #pragma unroll
            for (int c = 0; c < 4; c++) O[rt][dt][c] = 0.f;
    }

    f32x4 zero4;
    #pragma unroll
    for (int c = 0; c < 4; c++) zero4[c] = 0.f;
    bf16x8 ones;
    #pragma unroll
    for (int c = 0; c < 8; c++) ones[c] = (short)0x3F80;   // bf16 1.0

    for (int st = 0; st < S_LEN / 128; st++) {
        __syncthreads();
        gld16(Ks + ((w + 0) * 2 + 0) * 512, gK);
        gld16(Ks + ((w + 0) * 2 + 1) * 512, gK + 32);
        gld16(Ks + ((w + 4) * 2 + 0) * 512, gK + (size_t)64 * DMODEL);
        gld16(Ks + ((w + 4) * 2 + 1) * 512, gK + (size_t)64 * DMODEL + 32);
        gld16(Vs + (w * 4 + 0) * 512, gV);
        gld16(Vs + (w * 4 + 1) * 512, gV + 32);
        gld16(Vs + (w * 4 + 2) * 512, gV + 64);
        gld16(Vs + (w * 4 + 3) * 512, gV + 96);
        gK += (size_t)128 * DMODEL;
        gV += 128;
        __syncthreads();

        #pragma unroll
        for (int r = 0; r < 4; r++) {
            f32x4 sc[2][2];
            {
                bf16x8 kf0 = *(const bf16x8*)&Ks[((r * 2 + 0) * 2 + 0) * 512 + lane * 8];
                bf16x8 kf1 = *(const bf16x8*)&Ks[((r * 2 + 1) * 2 + 0) * 512 + lane * 8];
                sc[0][0] = __builtin_amdgcn_mfma_f32_16x16x32_bf16(kf0, qf[0][0], zero4, 0, 0, 0);
                sc[0][1] = __builtin_amdgcn_mfma_f32_16x16x32_bf16(kf0, qf[1][0], zero4, 0, 0, 0);
                sc[1][0] = __builtin_amdgcn_mfma_f32_16x16x32_bf16(kf1, qf[0][0], zero4, 0, 0, 0);
                sc[1][1] = __builtin_amdgcn_mfma_f32_16x16x32_bf16(kf1, qf[1][0], zero4, 0, 0, 0);
                kf0 = *(const bf16x8*)&Ks[((r * 2 + 0) * 2 + 1) * 512 + lane * 8];
                kf1 = *(const bf16x8*)&Ks[((r * 2 + 1) * 2 + 1) * 512 + lane * 8];
                sc[0][0] = __builtin_amdgcn_mfma_f32_16x16x32_bf16(kf0, qf[0][1], sc[0][0], 0, 0, 0);
                sc[0][1] = __builtin_amdgcn_mfma_f32_16x16x32_bf16(kf0, qf[1][1], sc[0][1], 0, 0, 0);
                sc[1][0] = __builtin_amdgcn_mfma_f32_16x16x32_bf16(kf1, qf[0][1], sc[1][0], 0, 0, 0);
                sc[1][1] = __builtin_amdgcn_mfma_f32_16x16x32_bf16(kf1, qf[1][1], sc[1][1], 0, 0, 0);
            }

            #pragma unroll
            for (int nt = 0; nt < 2; nt++) {
                #pragma unroll
                for (int mt = 0; mt < 2; mt++) {
                    unsigned u[4];
                    #pragma unroll
                    for (int c = 0; c < 4; c++)
                        u[c] = __float_as_uint(__builtin_amdgcn_exp2f(sc[mt][nt][c]));
                    uint2 pk;
                    pk.x = __builtin_amdgcn_perm(u[1], u[0], 0x07060302u);
                    pk.y = __builtin_amdgcn_perm(u[3], u[2], 0x07060302u);
                    int off = (w * 2 + nt) * 512 + (mt * 2 + (quad >> 1)) * 128 +
                              l15 * 8 + (quad & 1) * 4;
                    *(uint2*)&Ps[off] = pk;
                }
            }

            bf16x8 pf0 = *(const bf16x8*)&Ps[(w * 2 + 0) * 512 + lane * 8];
            bf16x8 pf1 = *(const bf16x8*)&Ps[(w * 2 + 1) * 512 + lane * 8];
            lsum[0] = __builtin_amdgcn_mfma_f32_16x16x32_bf16(pf0, ones, lsum[0], 0, 0, 0);
            lsum[1] = __builtin_amdgcn_mfma_f32_16x16x32_bf16(pf1, ones, lsum[1], 0, 0, 0);
            #pragma unroll
            for (int dt = 0; dt < 4; dt++) {
                bf16x8 vf = *(const bf16x8*)&Vs[(dt * 4 + r) * 512 + lane * 8];
                O[0][dt] = __builtin_amdgcn_mfma_f32_16x16x32_bf16(pf0, vf, O[0][dt], 0, 0, 0);
                O[1][dt] = __builtin_amdgcn_mfma_f32_16x16x32_bf16(pf1, vf, O[1][dt], 0, 0, 0);
            }
        }
    }

    const size_t srow = (size_t)(b * S_LEN + r0 + w * 32);
    #pragma unroll
    for (int rt = 0; rt < 2; rt++) {
        #pragma unroll
        for (int reg = 0; reg < 4; reg++) {
            float li = 1.0f / lsum[rt][reg];
            size_t rowoff = (srow + rt * 16 + quad * 4 + reg) * DMODEL + h * HD + l15;
            #pragma unroll
            for (int dt = 0; dt < 4; dt++)
                ctxb[rowoff + dt * 16] = f2bf_rne(O[rt][dt][reg] * li);
        }
    }
}

// ---------------------------------------------------------------------------
// Kernel 3: output projection v4, 8-way K-split.  512 blocks x 512 thr
// (16 waves/CU, exactly 2 blocks/CU = 1 dispatch round).  Block = 16 rows;
// wave w reduces K slice [w*128,(w+1)*128); 32 KB LDS reduce + one barrier.
// ---------------------------------------------------------------------------
__global__ __launch_bounds__(512) void out_proj_mfma(
    const unsigned short* __restrict__ ctxb,
    const unsigned short* __restrict__ WfT,
    const float* __restrict__ bfb,
    float* __restrict__ out)
{
    __shared__ float Red[8 * 1024];   // [wave][lane][j*4+reg], 32 KB

    const int tid = threadIdx.x;
    const int lane = tid & 63, w = tid >> 6;    // w 0..7
    const int quad = lane >> 4, l15 = lane & 15;
    const int m0 = blockIdx.x * 16;

    const unsigned short* pA = ctxb + (size_t)(m0 + l15) * DMODEL + w * 128 + quad * 8;
    const unsigned short* pB = WfT + (size_t)l15 * DMODEL + w * 128 + quad * 8;

    f32x4 acc[4];
    #pragma unroll
    for (int j = 0; j < 4; j++)
        #pragma unroll
        for (int c = 0; c < 4; c++) acc[j][c] = 0.f;

    #pragma unroll
    for (int k0 = 0; k0 < 128; k0 += 32) {
        bf16x8 af = *(const bf16x8*)(pA + k0);
        #pragma unroll
        for (int j = 0; j < 4; j++) {
            bf16x8 bfr = *(const bf16x8*)(pB + (size_t)j * 16 * DMODEL + k0);
            acc[j] = __builtin_amdgcn_mfma_f32_16x16x32_bf16(af, bfr, acc[j], 0, 0, 0);
        }
    }

    #pragma unroll
    for (int j = 0; j < 4; j++)
        #pragma unroll
        for (int reg = 0; reg < 4; reg++)
            Red[w * 1024 + lane * 16 + j * 4 + reg] = acc[j][reg];
    __syncthreads();

    // reducer: 512 thr -> 1024 outputs (2 adjacent cols each)
    const int row = tid >> 5;          // 0..15
    const int c0  = (tid & 31) * 2;    // 0..62
    float2 o;
    float* op = &o.x;
    #pragma unroll
    for (int cc = 0; cc < 2; cc++) {
        int col = c0 + cc;
        int idx = ((row >> 2) * 16 + (col & 15)) * 16 + (col >> 4) * 4 + (row & 3);
        float s = 0.f;
        #pragma unroll
        for (int wv = 0; wv < 8; wv++) s += Red[wv * 1024 + idx];
        op[cc] = s + bfb[col];
    }
    *(float2*)(out + (size_t)(m0 + row) * HD + c0) = o;
}

// ---------------------------------------------------------------------------
extern "C" void kernel_launch(void* const* d_in, const int* in_sizes, int n_in,
                              void* d_out, int out_size, void* d_ws, size_t ws_size,
                              hipStream_t stream)
{
    (void)in_sizes; (void)n_in; (void)out_size; (void)ws_size;
    const float* x  = (const float*)d_in[0];
    const float* Wq = (const float*)d_in[1];
    const float* bq = (const float*)d_in[2];
    const float* Wk = (const float*)d_in[3];
    const float* bk = (const float*)d_in[4];
    const float* Wv = (const float*)d_in[5];
    const float* bv = (const float*)d_in[6];
    const float* Wf = (const float*)d_in[7];
    const float* bf = (const float*)d_in[8];
    float* out = (float*)d_out;

    char* wsb = (char*)d_ws;
    unsigned short* xb   = (unsigned short*)wsb;            // 16 MB, dead after qkv
    unsigned short* ctxb = (unsigned short*)wsb;            // reuses xb region
    unsigned short* WT   = xb + (size_t)M_TOT * DMODEL;     // 3x2 MB + WfT
    unsigned short* WfT  = WT + (size_t)3 * DMODEL * DMODEL;
    unsigned short* Qb   = (unsigned short*)(wsb + (size_t)32 * 1024 * 1024);
    unsigned short* Kb   = Qb + (size_t)M_TOT * DMODEL;
    unsigned short* Vtb  = Kb + (size_t)M_TOT * DMODEL;

    cvt_fused<<<dim3(16, 16, 5), 256, 0, stream>>>(x, Wq, Wk, Wv, Wf, xb, WT);
    qkv_gemm_mfma<<<dim3(8, 64, 3), 256, 0, stream>>>(xb, WT, bq, bk, bv, Qb, Kb, Vtb);
    flash_attn_mfma<<<dim3(S_LEN / 128, NH, BATCH), 256, 0, stream>>>(Qb, Kb, Vtb, ctxb);
    out_proj_mfma<<<dim3(M_TOT / 16), 512, 0, stream>>>(ctxb, WfT, bf, out);
}

// Round 13
// 285.296 us; speedup vs baseline: 3.1302x; 1.0183x over previous
//
#include <hip/hip_runtime.h>
#include <math.h>

#define S_LEN 2048
#define NH 16
#define HD 64
#define DMODEL 1024
#define BATCH 4
#define M_TOT (BATCH * S_LEN)   // 8192

typedef __attribute__((ext_vector_type(8))) short bf16x8;
typedef __attribute__((ext_vector_type(4))) float f32x4;

#define CK 0.18033688f   // (1/sqrt(64)) * log2(e), folded into Q at projection

__device__ __forceinline__ unsigned short f2bf_rne(float f) {
    unsigned u = __float_as_uint(f);
    u += 0x7fffu + ((u >> 16) & 1u);
    return (unsigned short)(u >> 16);
}

__device__ __forceinline__ void gld16(unsigned short* lds, const unsigned short* g) {
    __builtin_amdgcn_global_load_lds(
        (const __attribute__((address_space(1))) void*)g,
        (__attribute__((address_space(3))) void*)lds, 16, 0, 0);
}

// ---------------------------------------------------------------------------
// cvt_fused: one dispatch for all input conversion.
// z=0..2: Wq/Wk/Wv [k][n] fp32 -> WT [n][k] bf16 (64x64 transpose tiles)
// z=3:    Wf (1024x64) -> WfT [64][1024]   (only blockIdx.x==0 active)
// z=4:    x fp32 -> bf16 (256 blocks x 32 float4/thread)
// ---------------------------------------------------------------------------
__global__ __launch_bounds__(256) void cvt_fused(
    const float* __restrict__ x,
    const float* __restrict__ Wq, const float* __restrict__ Wk,
    const float* __restrict__ Wv, const float* __restrict__ Wf,
    unsigned short* __restrict__ xb, unsigned short* __restrict__ WT)
{
    const int z = blockIdx.z;
    const int tid = threadIdx.x;

    if (z < 4) {
        if (z == 3 && blockIdx.x > 0) return;
        const float* W = (z == 0) ? Wq : (z == 1) ? Wk : (z == 2) ? Wv : Wf;
        const int ncol = (z == 3) ? 64 : DMODEL;
        unsigned short* out = WT + (size_t)z * DMODEL * DMODEL;

        __shared__ float Lt[64][65];
        const int r0 = blockIdx.y * 64;
        const int c0 = blockIdx.x * 64;

        #pragma unroll
        for (int p = 0; p < 4; p++) {
            int row = (tid >> 4) + p * 16;
            int c4 = (tid & 15) * 4;
            float4 v = *(const float4*)(W + (size_t)(r0 + row) * ncol + c0 + c4);
            Lt[row][c4 + 0] = v.x; Lt[row][c4 + 1] = v.y;
            Lt[row][c4 + 2] = v.z; Lt[row][c4 + 3] = v.w;
        }
        __syncthreads();
        #pragma unroll
        for (int p = 0; p < 4; p++) {
            int nr = (tid >> 4) + p * 16;
            int kc = (tid & 15) * 4;
            unsigned short t[4];
            #pragma unroll
            for (int j = 0; j < 4; j++) t[j] = f2bf_rne(Lt[kc + j][nr]);
            *(uint2*)(out + (size_t)(c0 + nr) * DMODEL + r0 + kc) = *(uint2*)t;
        }
    } else {
        const int gtid = (blockIdx.y * 16 + blockIdx.x) * 256 + tid;
        #pragma unroll
        for (int it = 0; it < 8; it++) {
            #pragma unroll
            for (int k = 0; k < 4; k++) {
                size_t i = ((size_t)((it * 4 + k) * 65536) + gtid) * 4;
                float4 v = *(const float4*)(x + i);
                unsigned short t[4];
                t[0] = f2bf_rne(v.x); t[1] = f2bf_rne(v.y);
                t[2] = f2bf_rne(v.z); t[3] = f2bf_rne(v.w);
                *(uint2*)(xb + i) = *(uint2*)t;
            }
        }
    }
}

// ---------------------------------------------------------------------------
// Kernel 1: QKV projection, bf16 MFMA 16x16x32, BK=64 — R8 compute structure
// + XCD-AWARE SWIZZLE: blocks are remapped so XCD k (round-robin lin%8 under
// the dispatch heuristic) owns row-tiles 8k..8k+7 for ALL (oc,z) combos.
// Per-XCD read set = 2 MB x (stays L2-resident) + 6 MB W -> chip fetch ~64 MB
// vs 200 MB unswizzled (R12 counters).  Correctness is mapping-independent.
// NOTE: do NOT add a min-waves launch_bounds (R10: VGPR 48 -> spill, 6x).
// ---------------------------------------------------------------------------
__global__ __launch_bounds__(256) void qkv_gemm_mfma(
    const unsigned short* __restrict__ xb,
    const unsigned short* __restrict__ WT,
    const float* __restrict__ bq, const float* __restrict__ bk,
    const float* __restrict__ bv,
    unsigned short* __restrict__ Qb, unsigned short* __restrict__ Kb,
    unsigned short* __restrict__ Vtb)
{
    __shared__ __align__(16) unsigned short As[16 * 512];
    __shared__ __align__(16) unsigned short Bs[16 * 512];

    // ---- XCD swizzle: lin -> (row-block rb, oc-block ocb, weight z) ----
    const int lin = blockIdx.x + 8 * (blockIdx.y + 64 * blockIdx.z);  // 0..1535
    const int xcd = lin & 7;
    const int s   = lin >> 3;            // 0..191 (slot within XCD)
    const int rb  = xcd * 8 + (s & 7);   // 0..63
    const int ocz = s >> 3;              // 0..23
    const int ocb = ocz & 7;
    const int z   = ocz >> 3;

    const unsigned short* Wz = WT + (size_t)z * DMODEL * DMODEL;
    const float* bias = (z == 0) ? bq : (z == 1) ? bk : bv;

    const int tid = threadIdx.x;
    const int lane = tid & 63, w = tid >> 6;
    const int quad = lane >> 4, l15 = lane & 15;
    const int wm = w & 1, wn = w >> 1;

    const int OC0 = ocb * 128;
    const int R0  = rb * 128;

    const unsigned short* gA0 = Wz + (size_t)(OC0 + w * 16 + l15) * DMODEL + quad * 8;
    const unsigned short* gA1 = gA0 + (size_t)64 * DMODEL;
    const unsigned short* gB0 = xb + (size_t)(R0 + w * 16 + l15) * DMODEL + quad * 8;
    const unsigned short* gB1 = gB0 + (size_t)64 * DMODEL;

    f32x4 acc[4][4];
    #pragma unroll
    for (int i = 0; i < 4; i++)
        #pragma unroll
        for (int j = 0; j < 4; j++)
            #pragma unroll
            for (int c = 0; c < 4; c++) acc[i][j][c] = 0.f;

    for (int k0 = 0; k0 < DMODEL; k0 += 64) {
        __syncthreads();
        gld16(As + ((w + 0) * 2 + 0) * 512, gA0 + k0);
        gld16(As + ((w + 0) * 2 + 1) * 512, gA0 + k0 + 32);
        gld16(As + ((w + 4) * 2 + 0) * 512, gA1 + k0);
        gld16(As + ((w + 4) * 2 + 1) * 512, gA1 + k0 + 32);
        gld16(Bs + ((w + 0) * 2 + 0) * 512, gB0 + k0);
        gld16(Bs + ((w + 0) * 2 + 1) * 512, gB0 + k0 + 32);
        gld16(Bs + ((w + 4) * 2 + 0) * 512, gB1 + k0);
        gld16(Bs + ((w + 4) * 2 + 1) * 512, gB1 + k0 + 32);
        __syncthreads();

        #pragma unroll
        for (int sl = 0; sl < 2; sl++) {
            bf16x8 af[4], bfr[4];
            #pragma unroll
            for (int t = 0; t < 4; t++) {
                af[t]  = *(const bf16x8*)&As[((wm * 4 + t) * 2 + sl) * 512 + lane * 8];
                bfr[t] = *(const bf16x8*)&Bs[((wn * 4 + t) * 2 + sl) * 512 + lane * 8];
            }
            if (z != 2) {
                #pragma unroll
                for (int mt = 0; mt < 4; mt++)
                    #pragma unroll
                    for (int nt = 0; nt < 4; nt++)
                        acc[mt][nt] = __builtin_amdgcn_mfma_f32_16x16x32_bf16(
                            af[mt], bfr[nt], acc[mt][nt], 0, 0, 0);
            } else {
                #pragma unroll
                for (int mt = 0; mt < 4; mt++)
                    #pragma unroll
                    for (int nt = 0; nt < 4; nt++)
                        acc[mt][nt] = __builtin_amdgcn_mfma_f32_16x16x32_bf16(
                            bfr[nt], af[mt], acc[mt][nt], 0, 0, 0);
            }
        }
    }

    if (z != 2) {
        unsigned short* out = (z == 0) ? Qb : Kb;
        const float qs = (z == 0) ? CK : 1.0f;
        #pragma unroll
        for (int mt = 0; mt < 4; mt++) {
            int oc = OC0 + wm * 64 + mt * 16 + quad * 4;
            float4 bv4 = *(const float4*)&bias[oc];
            #pragma unroll
            for (int nt = 0; nt < 4; nt++) {
                int row = R0 + wn * 64 + nt * 16 + l15;
                unsigned short t4[4];
                t4[0] = f2bf_rne((acc[mt][nt][0] + bv4.x) * qs);
                t4[1] = f2bf_rne((acc[mt][nt][1] + bv4.y) * qs);
                t4[2] = f2bf_rne((acc[mt][nt][2] + bv4.z) * qs);
                t4[3] = f2bf_rne((acc[mt][nt][3] + bv4.w) * qs);
                *(uint2*)(out + (size_t)row * DMODEL + oc) = *(uint2*)t4;
            }
        }
    } else {
        const int b = R0 >> 11;
        const int sbase = (R0 & 2047) + wn * 64;
        #pragma unroll
        for (int mt = 0; mt < 4; mt++) {
            int oc = OC0 + wm * 64 + mt * 16 + l15;
            float bvv = bias[oc];
            #pragma unroll
            for (int nt = 0; nt < 4; nt++) {
                int sq = sbase + nt * 16 + quad * 4;
                unsigned short t4[4];
                t4[0] = f2bf_rne(acc[mt][nt][0] + bvv);
                t4[1] = f2bf_rne(acc[mt][nt][1] + bvv);
                t4[2] = f2bf_rne(acc[mt][nt][2] + bvv);
                t4[3] = f2bf_rne(acc[mt][nt][3] + bvv);
                *(uint2*)(Vtb + (size_t)(b * DMODEL + oc) * S_LEN + sq) = *(uint2*)t4;
            }
        }
    }
}

// ---------------------------------------------------------------------------
// Kernel 2: flash attention — R8 structure (measured optimum) + XCD-AWARE
// SWIZZLE: all 16 q-tile blocks of one (b,h) map to the same XCD (bh%8), so
// that (b,h)'s K/V stream is fetched once per XCD instead of up to 8x.
// Chip fetch ~48 MB vs 140 MB unswizzled (R12 counters).
// ---------------------------------------------------------------------------
__global__ __launch_bounds__(256, 4) void flash_attn_mfma(
    const unsigned short* __restrict__ Qg,   // [B*S,1024] bf16, pre-scaled by CK
    const unsigned short* __restrict__ Kg,   // [B*S,1024] bf16
    const unsigned short* __restrict__ Vtg,  // [B,H,64,S] bf16
    unsigned short* __restrict__ ctxb)       // [B*S,1024] bf16
{
    __shared__ __align__(16) unsigned short Ks[16 * 512];  // 16 KB
    __shared__ __align__(16) unsigned short Vs[16 * 512];  // 16 KB
    __shared__ __align__(16) unsigned short Ps[8 * 512];   //  8 KB

    const int tid  = threadIdx.x;
    const int lane = tid & 63, w = tid >> 6;
    const int quad = lane >> 4, l15 = lane & 15;

    // ---- XCD swizzle: lin -> (qblk, b, h) with bh%8 == lin%8 ----
    const int lin = blockIdx.x + 16 * (blockIdx.y + 16 * blockIdx.z);  // 0..1023
    const int xcd = lin & 7;
    const int s   = lin >> 3;              // 0..127
    const int bh  = xcd + 8 * (s >> 4);    // 0..63, bh%8 == xcd
    const int qblk = s & 15;
    const int b = bh >> 4, h = bh & 15;
    const int r0 = qblk * 128;

    bf16x8 qf[2][2];
    #pragma unroll
    for (int nt = 0; nt < 2; nt++)
        #pragma unroll
        for (int ds = 0; ds < 2; ds++)
            qf[nt][ds] = *(const bf16x8*)(Qg +
                (size_t)(b * S_LEN + r0 + w * 32 + nt * 16 + l15) * DMODEL +
                h * HD + ds * 32 + quad * 8);

    const unsigned short* gK = Kg + (size_t)(b * S_LEN + w * 16 + l15) * DMODEL + h * HD + quad * 8;
    const unsigned short* gV = Vtg + ((size_t)((b * NH + h) * HD + w * 16 + l15)) * S_LEN + quad * 8;

    f32x4 O[2][4], lsum[2];
    #pragma unroll
    for (int rt = 0; rt < 2; rt++) {
        #pragma unroll
        for (int c = 0; c < 4; c++) lsum[rt][c] = 0.f;
        #pragma unroll
        for (int dt = 0; dt < 4; dt++)
            #pragma unroll
            for (int c = 0; c < 4; c++) O[rt][dt][c] = 0.f;
    }

    f32x4 zero4;
    #pragma unroll
    for (int c = 0; c < 4; c++) zero4[c] = 0.f;
    bf16x8 ones;
    #pragma unroll
    for (int c = 0; c < 8; c++) ones[c] = (short)0x3F80;   // bf16 1.0

    for (int st = 0; st < S_LEN / 128; st++) {
        __syncthreads();
        gld16(Ks + ((w + 0) * 2 + 0) * 512, gK);
        gld16(Ks + ((w + 0) * 2 + 1) * 512, gK + 32);
        gld16(Ks + ((w + 4) * 2 + 0) * 512, gK + (size_t)64 * DMODEL);
        gld16(Ks + ((w + 4) * 2 + 1) * 512, gK + (size_t)64 * DMODEL + 32);
        gld16(Vs + (w * 4 + 0) * 512, gV);
        gld16(Vs + (w * 4 + 1) * 512, gV + 32);
        gld16(Vs + (w * 4 + 2) * 512, gV + 64);
        gld16(Vs + (w * 4 + 3) * 512, gV + 96);
        gK += (size_t)128 * DMODEL;
        gV += 128;
        __syncthreads();

        #pragma unroll
        for (int r = 0; r < 4; r++) {
            f32x4 sc[2][2];
            {
                bf16x8 kf0 = *(const bf16x8*)&Ks[((r * 2 + 0) * 2 + 0) * 512 + lane * 8];
                bf16x8 kf1 = *(const bf16x8*)&Ks[((r * 2 + 1) * 2 + 0) * 512 + lane * 8];
                sc[0][0] = __builtin_amdgcn_mfma_f32_16x16x32_bf16(kf0, qf[0][0], zero4, 0, 0, 0);
                sc[0][1] = __builtin_amdgcn_mfma_f32_16x16x32_bf16(kf0, qf[1][0], zero4, 0, 0, 0);
                sc[1][0] = __builtin_amdgcn_mfma_f32_16x16x32_bf16(kf1, qf[0][0], zero4, 0, 0, 0);
                sc[1][1] = __builtin_amdgcn_mfma_f32_16x16x32_bf16(kf1, qf[1][0], zero4, 0, 0, 0);
                kf0 = *(const bf16x8*)&Ks[((r * 2 + 0) * 2 + 1) * 512 + lane * 8];
                kf1 = *(const bf16x8*)&Ks[((r * 2 + 1) * 2 + 1) * 512 + lane * 8];
                sc[0][0] = __builtin_amdgcn_mfma_f32_16x16x32_bf16(kf0, qf[0][1], sc[0][0], 0, 0, 0);
                sc[0][1] = __builtin_amdgcn_mfma_f32_16x16x32_bf16(kf0, qf[1][1], sc[0][1], 0, 0, 0);
                sc[1][0] = __builtin_amdgcn_mfma_f32_16x16x32_bf16(kf1, qf[0][1], sc[1][0], 0, 0, 0);
                sc[1][1] = __builtin_amdgcn_mfma_f32_16x16x32_bf16(kf1, qf[1][1], sc[1][1], 0, 0, 0);
            }

            #pragma unroll
            for (int nt = 0; nt < 2; nt++) {
                #pragma unroll
                for (int mt = 0; mt < 2; mt++) {
                    unsigned u[4];
                    #pragma unroll
                    for (int c = 0; c < 4; c++)
                        u[c] = __float_as_uint(__builtin_amdgcn_exp2f(sc[mt][nt][c]));
                    uint2 pk;
                    pk.x = __builtin_amdgcn_perm(u[1], u[0], 0x07060302u);
                    pk.y = __builtin_amdgcn_perm(u[3], u[2], 0x07060302u);
                    int off = (w * 2 + nt) * 512 + (mt * 2 + (quad >> 1)) * 128 +
                              l15 * 8 + (quad & 1) * 4;
                    *(uint2*)&Ps[off] = pk;
                }
            }

            bf16x8 pf0 = *(const bf16x8*)&Ps[(w * 2 + 0) * 512 + lane * 8];
            bf16x8 pf1 = *(const bf16x8*)&Ps[(w * 2 + 1) * 512 + lane * 8];
            lsum[0] = __builtin_amdgcn_mfma_f32_16x16x32_bf16(pf0, ones, lsum[0], 0, 0, 0);
            lsum[1] = __builtin_amdgcn_mfma_f32_16x16x32_bf16(pf1, ones, lsum[1], 0, 0, 0);
            #pragma unroll
            for (int dt = 0; dt < 4; dt++) {
                bf16x8 vf = *(const bf16x8*)&Vs[(dt * 4 + r) * 512 + lane * 8];
                O[0][dt] = __builtin_amdgcn_mfma_f32_16x16x32_bf16(pf0, vf, O[0][dt], 0, 0, 0);
                O[1][dt] = __builtin_amdgcn_mfma_f32_16x16x32_bf16(pf1, vf, O[1][dt], 0, 0, 0);
            }
        }
    }

    const size_t srow = (size_t)(b * S_LEN + r0 + w * 32);
    #pragma unroll
    for (int rt = 0; rt < 2; rt++) {
        #pragma unroll
        for (int reg = 0; reg < 4; reg++) {
            float li = 1.0f / lsum[rt][reg];
            size_t rowoff = (srow + rt * 16 + quad * 4 + reg) * DMODEL + h * HD + l15;
            #pragma unroll
            for (int dt = 0; dt < 4; dt++)
                ctxb[rowoff + dt * 16] = f2bf_rne(O[rt][dt][reg] * li);
        }
    }
}

// ---------------------------------------------------------------------------
// Kernel 3: output projection v4, 8-way K-split.  512 blocks x 512 thr.
// ---------------------------------------------------------------------------
__global__ __launch_bounds__(512) void out_proj_mfma(
    const unsigned short* __restrict__ ctxb,
    const unsigned short* __restrict__ WfT,
    const float* __restrict__ bfb,
    float* __restrict__ out)
{
    __shared__ float Red[8 * 1024];   // [wave][lane][j*4+reg], 32 KB

    const int tid = threadIdx.x;
    const int lane = tid & 63, w = tid >> 6;    // w 0..7
    const int quad = lane >> 4, l15 = lane & 15;
    const int m0 = blockIdx.x * 16;

    const unsigned short* pA = ctxb + (size_t)(m0 + l15) * DMODEL + w * 128 + quad * 8;
    const unsigned short* pB = WfT + (size_t)l15 * DMODEL + w * 128 + quad * 8;

    f32x4 acc[4];
    #pragma unroll
    for (int j = 0; j < 4; j++)
        #pragma unroll
        for (int c = 0; c < 4; c++) acc[j][c] = 0.f;

    #pragma unroll
    for (int k0 = 0; k0 < 128; k0 += 32) {
        bf16x8 af = *(const bf16x8*)(pA + k0);
        #pragma unroll
        for (int j = 0; j < 4; j++) {
            bf16x8 bfr = *(const bf16x8*)(pB + (size_t)j * 16 * DMODEL + k0);
            acc[j] = __builtin_amdgcn_mfma_f32_16x16x32_bf16(af, bfr, acc[j], 0, 0, 0);
        }
    }

    #pragma unroll
    for (int j = 0; j < 4; j++)
        #pragma unroll
        for (int reg = 0; reg < 4; reg++)
            Red[w * 1024 + lane * 16 + j * 4 + reg] = acc[j][reg];
    __syncthreads();

    const int row = tid >> 5;          // 0..15
    const int c0  = (tid & 31) * 2;    // 0..62
    float2 o;
    float* op = &o.x;
    #pragma unroll
    for (int cc = 0; cc < 2; cc++) {
        int col = c0 + cc;
        int idx = ((row >> 2) * 16 + (col & 15)) * 16 + (col >> 4) * 4 + (row & 3);
        float s = 0.f;
        #pragma unroll
        for (int wv = 0; wv < 8; wv++) s += Red[wv * 1024 + idx];
        op[cc] = s + bfb[col];
    }
    *(float2*)(out + (size_t)(m0 + row) * HD + c0) = o;
}

// ---------------------------------------------------------------------------
extern "C" void kernel_launch(void* const* d_in, const int* in_sizes, int n_in,
                              void* d_out, int out_size, void* d_ws, size_t ws_size,
                              hipStream_t stream)
{
    (void)in_sizes; (void)n_in; (void)out_size; (void)ws_size;
    const float* x  = (const float*)d_in[0];
    const float* Wq = (const float*)d_in[1];
    const float* bq = (const float*)d_in[2];
    const float* Wk = (const float*)d_in[3];
    const float* bk = (const float*)d_in[4];
    const float* Wv = (const float*)d_in[5];
    const float* bv = (const float*)d_in[6];
    const float* Wf = (const float*)d_in[7];
    const float* bf = (const float*)d_in[8];
    float* out = (float*)d_out;

    char* wsb = (char*)d_ws;
    unsigned short* xb   = (unsigned short*)wsb;            // 16 MB, dead after qkv
    unsigned short* ctxb = (unsigned short*)wsb;            // reuses xb region
    unsigned short* WT   = xb + (size_t)M_TOT * DMODEL;     // 3x2 MB + WfT
    unsigned short* WfT  = WT + (size_t)3 * DMODEL * DMODEL;
    unsigned short* Qb   = (unsigned short*)(wsb + (size_t)32 * 1024 * 1024);
    unsigned short* Kb   = Qb + (size_t)M_TOT * DMODEL;
    unsigned short* Vtb  = Kb + (size_t)M_TOT * DMODEL;

    cvt_fused<<<dim3(16, 16, 5), 256, 0, stream>>>(x, Wq, Wk, Wv, Wf, xb, WT);
    qkv_gemm_mfma<<<dim3(8, 64, 3), 256, 0, stream>>>(xb, WT, bq, bk, bv, Qb, Kb, Vtb);
    flash_attn_mfma<<<dim3(S_LEN / 128, NH, BATCH), 256, 0, stream>>>(Qb, Kb, Vtb, ctxb);
    out_proj_mfma<<<dim3(M_TOT / 16), 512, 0, stream>>>(ctxb, WfT, bf, out);
}